// Round 6
// baseline (503.128 us; speedup 1.0000x reference)
//
#include <hip/hip_runtime.h>
#include <hip/hip_bf16.h>

// Swin block, MI355X. Layouts:
//  x: (768, 96, 96) f32 CHW.  tokens: row-major (tok, C) bf16.
//  windowed token order: w = wh*12+ww, n = i*8+j, shifted pixel = ((wh*8+i+4)%96, (ww*8+j+4)%96)

typedef __attribute__((ext_vector_type(8))) short bf16x8;
typedef __attribute__((ext_vector_type(4))) float f32x4;

__device__ __forceinline__ short f2bf(float f){
  unsigned u = __builtin_bit_cast(unsigned, f);
  unsigned r = (u + 0x7FFFu + ((u >> 16) & 1u)) >> 16;
  return (short)r;
}
__device__ __forceinline__ float bf2f(short s){
  unsigned u = ((unsigned)(unsigned short)s) << 16;
  return __builtin_bit_cast(float, u);
}
__device__ __forceinline__ float gelu_tanh(float v){
  const float c = 0.7978845608028654f;
  float u = c * (v + 0.044715f * v * v * v);
  float e = __expf(2.f * u);
  float th = 1.f - 2.f / (e + 1.f);
  return 0.5f * v * (1.f + th);
}
__device__ __forceinline__ void gl2lds16(const short* g, short* l){
  __builtin_amdgcn_global_load_lds(
      (const __attribute__((address_space(1))) int*)g,
      (__attribute__((address_space(3))) int*)l, 16, 0, 0);
}

// ---------------- weight f32 -> bf16 ----------------
__global__ void k_f2b(const float* __restrict__ in, short* __restrict__ out, int n){
  int i = blockIdx.x * 256 + threadIdx.x;
  if (i < n) out[i] = f2bf(in[i]);
}

// ---------------- precompute rel-pos bias per (h, m, n) ----------------
__global__ void k_bias_pre(const float* __restrict__ btab, float* __restrict__ biasp){
  int idx = blockIdx.x * 256 + threadIdx.x;   // h*4096 + m*64 + n
  int h = idx >> 12, mn = idx & 4095, m = mn >> 6, n = mn & 63;
  int i1 = m >> 3, j1 = m & 7, i2 = n >> 3, j2 = n & 7;
  biasp[idx] = btab[((i1 - i2 + 7) * 15 + (j1 - j2 + 7)) * 24 + h];
}

// ---------------- LN stats: per-pixel sum/sumsq over channels ----------------
__global__ void k_ln_stats(const float* __restrict__ x, float* __restrict__ sums,
                           float* __restrict__ sumsq){
  const int p = blockIdx.x * 256 + threadIdx.x;   // 0..9215
  const int c0 = blockIdx.y * 64;
  float s = 0.f, s2 = 0.f;
  for (int c = c0; c < c0 + 64; ++c){
    float v = x[(long)c * 9216 + p];
    s += v; s2 += v * v;
  }
  atomicAdd(&sums[p], s);
  atomicAdd(&sumsq[p], s2);
}
__global__ void k_ln_fin(const float* __restrict__ sums, const float* __restrict__ sumsq,
                         float* __restrict__ mean, float* __restrict__ rstd){
  const int p = blockIdx.x * 256 + threadIdx.x;
  float m = sums[p] * (1.f / 768.f);
  float v = sumsq[p] * (1.f / 768.f) - m * m;
  mean[p] = m;
  rstd[p] = rsqrtf(v + 1e-5f);
}

// ---------------- LN1 + shift + window partition -> bf16 tokens ----------------
__global__ void k_ln1_win(const float* __restrict__ x, const float* __restrict__ mean,
                          const float* __restrict__ rstd, const float* __restrict__ g,
                          const float* __restrict__ b, short* __restrict__ tok){
  __shared__ float tile[64][65];
  const int w = blockIdx.x, ct = blockIdx.y * 64;
  const int wh = w / 12, ww = w - wh * 12;
  const int t = threadIdx.x;
  for (int e = t; e < 4096; e += 256){        // lanes over pixels
    const int cl = e >> 6, pix = e & 63;
    int pr = wh * 8 + (pix >> 3) + 4; if (pr >= 96) pr -= 96;
    int pc = ww * 8 + (pix & 7) + 4;  if (pc >= 96) pc -= 96;
    tile[pix][cl] = x[(long)(ct + cl) * 9216 + pr * 96 + pc];
  }
  __syncthreads();
  for (int e = t; e < 4096; e += 256){        // lanes over channels
    const int pix = e >> 6, cl = e & 63;
    int pr = wh * 8 + (pix >> 3) + 4; if (pr >= 96) pr -= 96;
    int pc = ww * 8 + (pix & 7) + 4;  if (pc >= 96) pc -= 96;
    const int p = pr * 96 + pc;
    float v = (tile[pix][cl] - mean[p]) * rstd[p] * g[ct + cl] + b[ct + cl];
    tok[(long)(w * 64 + pix) * 768 + ct + cl] = f2bf(v);
  }
}

// ---------------- windowed residual merge: x1 = x + scatter(ptok) ----------------
__global__ void k_merge_win(const float* __restrict__ x, const short* __restrict__ ptok,
                            float* __restrict__ x1){
  __shared__ float tile[64][65];
  const int w = blockIdx.x, ct = blockIdx.y * 64;
  const int wh = w / 12, ww = w - wh * 12;
  const int t = threadIdx.x;
  for (int e = t; e < 4096; e += 256){        // lanes over channels (coalesced bf16 read)
    const int pix = e >> 6, cl = e & 63;
    tile[pix][cl] = bf2f(ptok[(long)(w * 64 + pix) * 768 + ct + cl]);
  }
  __syncthreads();
  for (int e = t; e < 4096; e += 256){        // lanes over pixels
    const int cl = e >> 6, pix = e & 63;
    int pr = wh * 8 + (pix >> 3) + 4; if (pr >= 96) pr -= 96;
    int pc = ww * 8 + (pix & 7) + 4;  if (pc >= 96) pc -= 96;
    const long gi = (long)(ct + cl) * 9216 + pr * 96 + pc;
    x1[gi] = x[gi] + tile[pix][cl];
  }
}

// ---------------- LN2 (raster order) -> bf16 tokens ----------------
__global__ void k_ln2_raster(const float* __restrict__ x1, const float* __restrict__ mean,
                             const float* __restrict__ rstd, const float* __restrict__ g,
                             const float* __restrict__ b, short* __restrict__ tok){
  __shared__ float tile[96][65];
  const int hrow = blockIdx.x, ct = blockIdx.y * 64;
  const int t = threadIdx.x;
  for (int e = t; e < 6144; e += 256){
    const int cl = e / 96, p = e - cl * 96;
    tile[p][cl] = x1[(long)(ct + cl) * 9216 + hrow * 96 + p];
  }
  __syncthreads();
  for (int e = t; e < 6144; e += 256){
    const int p = e >> 6, cl = e & 63;
    const int gp = hrow * 96 + p;
    float v = (tile[p][cl] - mean[gp]) * rstd[gp] * g[ct + cl] + b[ct + cl];
    tok[(long)gp * 768 + ct + cl] = f2bf(v);
  }
}

// ---------------- final merge (raster): out = x1 + mtok ----------------
__global__ void k_merge_raster(const float* __restrict__ x1, const short* __restrict__ mtok,
                               float* __restrict__ out){
  __shared__ float tile[96][65];
  const int hrow = blockIdx.x, ct = blockIdx.y * 64;
  const int t = threadIdx.x;
  for (int e = t; e < 6144; e += 256){
    const int p = e >> 6, cl = e & 63;
    tile[p][cl] = bf2f(mtok[(long)(hrow * 96 + p) * 768 + ct + cl]);
  }
  __syncthreads();
  for (int e = t; e < 6144; e += 256){
    const int cl = e / 96, p = e - cl * 96;
    const long gi = (long)(ct + cl) * 9216 + hrow * 96 + p;
    out[gi] = x1[gi] + tile[p][cl];
  }
}

// ---------------- MFMA GEMM 128x128, BK=32, 4 waves, 2-phase + T2 swizzle ----------------
// rows = 64B = 4 slots of 16B; data for (row, slot s) stored at slot s^((row>>1)&3)
// via pre-swizzled global source (gl2lds dest stays linear).
__global__ __launch_bounds__(256) void k_gemm_bt(
    const short* __restrict__ A, const short* __restrict__ B,
    const float* __restrict__ bias, short* __restrict__ C,
    int N, int K, int NBN, int do_gelu)
{
  __shared__ short Al[2][4096];
  __shared__ short Bl[2][4096];
  const int tid = threadIdx.x;
  const int wave = tid >> 6, lane = tid & 63;
  const int l15 = lane & 15, lg = lane >> 4;

  const int nb = gridDim.x;
  const int q = nb >> 3, r = nb & 7;
  const int xcd = blockIdx.x & 7, loc = blockIdx.x >> 3;
  const int swz = (xcd < r ? xcd * (q + 1) : r * (q + 1) + (xcd - r) * q) + loc;
  const int bn = swz % NBN, bm = swz / NBN;

  const long Abase = (long)bm * 128 * K;
  const long Bbase = (long)bn * 128 * K;
  const int srow = tid >> 2;                              // staging row
  const int scol = ((tid & 3) ^ ((tid >> 3) & 3)) << 3;   // pre-swizzled slot
  const int x3 = (l15 >> 1) & 3;                          // read-side slot xor
  const int wr = (wave >> 1) * 64, wc = (wave & 1) * 64;

  f32x4 acc[4][4] = {};

  auto stage = [&](int buf, int k0){
    const short* gA = A + Abase + (long)srow * K + k0 + scol;
    const short* gB = B + Bbase + (long)srow * K + k0 + scol;
    short* lA = &Al[buf][wave * 512];
    short* lB = &Bl[buf][wave * 512];
    gl2lds16(gA, lA);
    gl2lds16(gA + (long)64 * K, lA + 2048);
    gl2lds16(gB, lB);
    gl2lds16(gB + (long)64 * K, lB + 2048);
  };

  const int NKT = K >> 5;
  stage(0, 0);
  asm volatile("s_waitcnt vmcnt(0)" ::: "memory");
  __builtin_amdgcn_s_barrier();

  int buf = 0;
  for (int kt = 0; kt < NKT; ++kt){
    if (kt + 1 < NKT) stage(buf ^ 1, (kt + 1) << 5);
    bf16x8 af[4], bfv[4];
    #pragma unroll
    for (int m = 0; m < 4; ++m)
      af[m] = *(const bf16x8*)&Al[buf][(wr + m * 16 + l15) * 32 + ((lg ^ x3) << 3)];
    #pragma unroll
    for (int n2 = 0; n2 < 4; ++n2)
      bfv[n2] = *(const bf16x8*)&Bl[buf][(wc + n2 * 16 + l15) * 32 + ((lg ^ x3) << 3)];
    asm volatile("s_waitcnt lgkmcnt(0)" ::: "memory");
    __builtin_amdgcn_sched_barrier(0);
    #pragma unroll
    for (int m = 0; m < 4; ++m)
      #pragma unroll
      for (int n2 = 0; n2 < 4; ++n2)
        acc[m][n2] = __builtin_amdgcn_mfma_f32_16x16x32_bf16(af[m], bfv[n2], acc[m][n2], 0, 0, 0);
    asm volatile("s_waitcnt vmcnt(0)" ::: "memory");
    __builtin_amdgcn_s_barrier();
    buf ^= 1;
  }

  const long row0 = (long)bm * 128 + wr + lg * 4;
  const int col0 = bn * 128 + wc + l15;
  #pragma unroll
  for (int m = 0; m < 4; ++m){
    #pragma unroll
    for (int n2 = 0; n2 < 4; ++n2){
      const int col = col0 + n2 * 16;
      const float bb = bias[col];
      #pragma unroll
      for (int r2 = 0; r2 < 4; ++r2){
        float v = acc[m][n2][r2] + bb;
        if (do_gelu) v = gelu_tanh(v);
        C[(row0 + m * 16 + r2) * (long)N + col] = f2bf(v);
      }
    }
  }
}

// ---------------- MFMA GEMM 256x256, BK=64, 8 waves, 8-phase counted-vmcnt ----------------
// m201-template port. LDS 128KB: [buf][op][half][128 rows][64 cols] bf16, 128B rows.
// T2: slot(16B) s stored at s^(row&7) via pre-swizzled global source; read xor l15&7.
// Per K-tile 4 phases; stages: ph0 A1(t+1), ph1 B0(t+2), ph2 B1(t+2), ph3 A0(t+2);
// vmcnt(6) at each tile's last phase (after MFMA, before trailing barrier).
__global__ __launch_bounds__(512, 2) void k_gemm8(
    const short* __restrict__ A, const short* __restrict__ B,
    const float* __restrict__ bias, short* __restrict__ C,
    int N, int K, int NBN, int do_gelu)
{
  __shared__ short sm[65536];   // 128 KiB
  const int tid = threadIdx.x;
  const int w = tid >> 6, l = tid & 63;
  const int l15 = l & 15, lg = l >> 4;
  const int wm = w >> 2, wn = w & 3;
  const int x7 = l15 & 7;

  const int nb = gridDim.x;
  const int q = nb >> 3, r = nb & 7;
  const int xcd = blockIdx.x & 7, loc = blockIdx.x >> 3;
  const int swz = (xcd < r ? xcd * (q + 1) : r * (q + 1) + (xcd - r) * q) + loc;
  const int bn = swz % NBN, bm = swz / NBN;

  const long arow0 = (long)bm * 256, brow0 = (long)bn * 256;
  const int srow_base = w * 8 + (l >> 3);               // + rnd*64
  const int scol = ((l & 7) ^ (l >> 3)) << 3;           // pre-swizzled 16B slot

  f32x4 acc[8][4] = {};

  auto stageH = [&](int p2, int op, int h, int k0){
    const short* g = (op ? B + (brow0 + h * 128) * (long)K
                         : A + (arow0 + h * 128) * (long)K) + k0 + scol;
    short* lb = &sm[((p2 * 2 + op) * 2 + h) * 8192 + w * 512];
    gl2lds16(g + (long)srow_base * K, lb);
    gl2lds16(g + (long)(srow_base + 64) * K, lb + 4096);
  };

  // prologue: tile0 {B0,B1,A0,A1}, tile1 {B0,B1,A0} -> wait tile0 resident
  stageH(0, 1, 0, 0);  stageH(0, 1, 1, 0);  stageH(0, 0, 0, 0);  stageH(0, 0, 1, 0);
  stageH(1, 1, 0, 64); stageH(1, 1, 1, 64); stageH(1, 0, 0, 64);
  asm volatile("s_waitcnt vmcnt(6)" ::: "memory");
  __builtin_amdgcn_s_barrier();

#define GPH(f0, STAGE, TAIL)                                                   \
  {                                                                            \
    bf16x8 afr[2][2];                                                          \
    _Pragma("unroll")                                                          \
    for (int fi = 0; fi < 2; ++fi){                                            \
      const int fr = (f0) + fi;                                                \
      const int ra = abase + ((fr >> 2) * 8192)                                \
                   + (((fr & 3) * 32 + wm * 16 + l15) * 64);                   \
      _Pragma("unroll")                                                        \
      for (int ks = 0; ks < 2; ++ks)                                           \
        afr[fi][ks] = *(const bf16x8*)&sm[ra + (((ks * 4 + lg) ^ x7) << 3)];   \
    }                                                                          \
    STAGE;                                                                     \
    __builtin_amdgcn_s_barrier();                                              \
    asm volatile("s_waitcnt lgkmcnt(0)" ::: "memory");                         \
    __builtin_amdgcn_sched_barrier(0);                                         \
    __builtin_amdgcn_s_setprio(1);                                             \
    _Pragma("unroll")                                                          \
    for (int fi = 0; fi < 2; ++fi)                                             \
      _Pragma("unroll")                                                        \
      for (int nf = 0; nf < 4; ++nf)                                           \
        _Pragma("unroll")                                                      \
        for (int ks = 0; ks < 2; ++ks)                                         \
          acc[(f0) + fi][nf] = __builtin_amdgcn_mfma_f32_16x16x32_bf16(        \
              afr[fi][ks], bfr[nf][ks], acc[(f0) + fi][nf], 0, 0, 0);          \
    __builtin_amdgcn_s_setprio(0);                                             \
    TAIL;                                                                      \
    __builtin_amdgcn_s_barrier();                                              \
  }

  const int NT = K >> 6;
  for (int t = 0; t < NT; ++t){
    const int p = t & 1;
    const int abase = p * 32768;
    const int bbase = p * 32768 + 16384;
    const int k2 = (t + 2) << 6;
    const bool s2 = (t + 2 < NT);

    bf16x8 bfr[4][2];
    #pragma unroll
    for (int nf = 0; nf < 4; ++nf){
      const int row = wn * 64 + nf * 16 + l15;
      const int rb = bbase + ((row >> 7) * 8192) + ((row & 127) * 64);
      #pragma unroll
      for (int ks = 0; ks < 2; ++ks)
        bfr[nf][ks] = *(const bf16x8*)&sm[rb + (((ks * 4 + lg) ^ x7) << 3)];
    }

    GPH(0, if (t + 1 < NT) stageH(p ^ 1, 0, 1, (t + 1) << 6), )
    GPH(2, if (s2) stageH(p, 1, 0, k2), )
    GPH(4, if (s2) stageH(p, 1, 1, k2), )
    GPH(6, if (s2) stageH(p, 0, 0, k2),
        if (s2)              { asm volatile("s_waitcnt vmcnt(6)" ::: "memory"); } \
        else if (t + 1 < NT) { asm volatile("s_waitcnt vmcnt(0)" ::: "memory"); })
  }
#undef GPH

  // epilogue
  #pragma unroll
  for (int fr = 0; fr < 8; ++fr){
    const long row0 = (long)bm * 256 + fr * 32 + wm * 16 + lg * 4;
    #pragma unroll
    for (int nf = 0; nf < 4; ++nf){
      const int col = bn * 256 + wn * 64 + nf * 16 + l15;
      const float bb = bias[col];
      #pragma unroll
      for (int r2 = 0; r2 < 4; ++r2){
        float v = acc[fr][nf][r2] + bb;
        if (do_gelu) v = gelu_tanh(v);
        C[(row0 + r2) * (long)N + col] = f2bf(v);
      }
    }
  }
}

// ---------------- MFMA attention: one wave per (window, head) ----------------
#define PSTR 72
__global__ __launch_bounds__(256) void k_attn_mfma(
    const short* __restrict__ qkv, const float* __restrict__ biasp,
    short* __restrict__ out)
{
  __shared__ short Pl[4][64 * PSTR];
  const int tid = threadIdx.x, wv = tid >> 6, lane = tid & 63;
  const int l15 = lane & 15, lg = lane >> 4;
  const int task = blockIdx.x * 4 + wv;          // 0..3455
  const int w = task / 24, h = task - w * 24;
  const int wh = w / 12, ww = w - wh * 12;
  const long base = (long)w * 64 * 2304;
  const float scale = 0.17677669529663687f;      // 1/sqrt(32)

  bf16x8 qf[4], kf[4];
  #pragma unroll
  for (int mi = 0; mi < 4; ++mi)
    qf[mi] = *(const bf16x8*)(qkv + base + (long)(mi * 16 + l15) * 2304 + h * 32 + lg * 8);
  #pragma unroll
  for (int ni = 0; ni < 4; ++ni)
    kf[ni] = *(const bf16x8*)(qkv + base + (long)(ni * 16 + l15) * 2304 + 768 + h * 32 + lg * 8);

  f32x4 acc[4][4] = {};
  #pragma unroll
  for (int mi = 0; mi < 4; ++mi)
    #pragma unroll
    for (int ni = 0; ni < 4; ++ni)
      acc[mi][ni] = __builtin_amdgcn_mfma_f32_16x16x32_bf16(qf[mi], kf[ni], acc[mi][ni], 0, 0, 0);

  const float* bh = biasp + h * 4096;
  #pragma unroll
  for (int mi = 0; mi < 4; ++mi){
    #pragma unroll
    for (int r = 0; r < 4; ++r){
      const int m = mi * 16 + lg * 4 + r;
      const int i1 = m >> 3, j1 = m & 7;
      const int labm = ((wh == 11) ? ((i1 >= 4) ? 2 : 1) : 0) * 3
                     + ((ww == 11) ? ((j1 >= 4) ? 2 : 1) : 0);
      #pragma unroll
      for (int ni = 0; ni < 4; ++ni){
        const int n = ni * 16 + l15;
        const int i2 = n >> 3, j2 = n & 7;
        const int labn = ((wh == 11) ? ((i2 >= 4) ? 2 : 1) : 0) * 3
                       + ((ww == 11) ? ((j2 >= 4) ? 2 : 1) : 0);
        float s = acc[mi][ni][r] * scale + bh[m * 64 + n];
        if (labm != labn) s -= 100.f;
        acc[mi][ni][r] = s;
      }
    }
  }

  float inv[4][4];
  #pragma unroll
  for (int mi = 0; mi < 4; ++mi){
    #pragma unroll
    for (int r = 0; r < 4; ++r){
      float mx = fmaxf(fmaxf(acc[mi][0][r], acc[mi][1][r]),
                       fmaxf(acc[mi][2][r], acc[mi][3][r]));
      #pragma unroll
      for (int off = 1; off < 16; off <<= 1) mx = fmaxf(mx, __shfl_xor(mx, off));
      float sum = 0.f;
      #pragma unroll
      for (int ni = 0; ni < 4; ++ni){
        float e = __expf(acc[mi][ni][r] - mx);
        acc[mi][ni][r] = e;
        sum += e;
      }
      #pragma unroll
      for (int off = 1; off < 16; off <<= 1) sum += __shfl_xor(sum, off);
      inv[mi][r] = 1.f / sum;
    }
  }

  short* pw = &Pl[wv][0];
  #pragma unroll
  for (int mi = 0; mi < 4; ++mi)
    #pragma unroll
    for (int ni = 0; ni < 4; ++ni)
      #pragma unroll
      for (int r = 0; r < 4; ++r)
        pw[(mi * 16 + lg * 4 + r) * PSTR + ni * 16 + l15] = f2bf(acc[mi][ni][r]);
  __syncthreads();

  f32x4 acc2[4][2] = {};
  #pragma unroll
  for (int kk = 0; kk < 2; ++kk){
    bf16x8 pa[4], vb[2];
    #pragma unroll
    for (int mi = 0; mi < 4; ++mi)
      pa[mi] = *(const bf16x8*)&pw[(mi * 16 + l15) * PSTR + kk * 32 + lg * 8];
    #pragma unroll
    for (int dj = 0; dj < 2; ++dj){
      bf16x8 t;
      #pragma unroll
      for (int e = 0; e < 8; ++e)
        t[e] = qkv[base + (long)(kk * 32 + lg * 8 + e) * 2304 + 1536 + h * 32 + dj * 16 + l15];
      vb[dj] = t;
    }
    #pragma unroll
    for (int mi = 0; mi < 4; ++mi)
      #pragma unroll
      for (int dj = 0; dj < 2; ++dj)
        acc2[mi][dj] = __builtin_amdgcn_mfma_f32_16x16x32_bf16(pa[mi], vb[dj], acc2[mi][dj], 0, 0, 0);
  }

  #pragma unroll
  for (int mi = 0; mi < 4; ++mi){
    #pragma unroll
    for (int r = 0; r < 4; ++r){
      const int m = mi * 16 + lg * 4 + r;
      const long ob = (long)(w * 64 + m) * 768 + h * 32;
      #pragma unroll
      for (int dj = 0; dj < 2; ++dj)
        out[ob + dj * 16 + l15] = f2bf(acc2[mi][dj][r] * inv[mi][r]);
    }
  }
}

// ---------------- launch ----------------
extern "C" void kernel_launch(void* const* d_in, const int* in_sizes, int n_in,
                              void* d_out, int out_size, void* d_ws, size_t ws_size,
                              hipStream_t stream)
{
  const float* x      = (const float*)d_in[0];
  const float* n1w    = (const float*)d_in[1];
  const float* n1b    = (const float*)d_in[2];
  const float* qkv_w  = (const float*)d_in[3];
  const float* qkv_b  = (const float*)d_in[4];
  const float* proj_w = (const float*)d_in[5];
  const float* proj_b = (const float*)d_in[6];
  const float* btab   = (const float*)d_in[7];
  const float* n2w    = (const float*)d_in[8];
  const float* n2b    = (const float*)d_in[9];
  const float* fc1_w  = (const float*)d_in[10];
  const float* fc1_b  = (const float*)d_in[11];
  const float* fc2_w  = (const float*)d_in[12];
  const float* fc2_b  = (const float*)d_in[13];
  float* out = (float*)d_out;
  char* ws = (char*)d_ws;

  short* WQ   = (short*)(ws + 0);           // 2304x768 bf16
  short* WP   = (short*)(ws + 3538944);     // 768x768
  short* W1   = (short*)(ws + 4718592);     // 3072x768
  short* W2   = (short*)(ws + 9437184);     // 768x3072
  float* SUMS = (float*)(ws + 14155776);    // 9216
  float* SUMSQ= (float*)(ws + 14192640);    // 9216
  float* MEAN = (float*)(ws + 14229504);
  float* RSTD = (float*)(ws + 14266368);
  float* BIASP= (float*)(ws + 14303232);    // 24*64*64 f32
  short* TOK  = (short*)(ws + 14696448);    // 9216x768 bf16
  short* BIG  = (short*)(ws + 28852224);    // 9216x2304 (qkv) / 9216x3072 (hid)
  short* ATT  = (short*)(ws + 85475328);    // 9216x768
  short* PRJ  = (short*)(ws + 99631104);    // 9216x768
  float* X1   = (float*)(ws + 113786880);   // 768x9216 f32

  k_f2b<<<(2304 * 768 + 255) / 256, 256, 0, stream>>>(qkv_w, WQ, 2304 * 768);
  k_f2b<<<(768 * 768 + 255) / 256, 256, 0, stream>>>(proj_w, WP, 768 * 768);
  k_f2b<<<(3072 * 768 + 255) / 256, 256, 0, stream>>>(fc1_w, W1, 3072 * 768);
  k_f2b<<<(768 * 3072 + 255) / 256, 256, 0, stream>>>(fc2_w, W2, 768 * 3072);
  k_bias_pre<<<(24 * 4096) / 256, 256, 0, stream>>>(btab, BIASP);

  hipMemsetAsync(SUMS, 0, 2 * 9216 * 4, stream);
  k_ln_stats<<<dim3(36, 12), 256, 0, stream>>>(x, SUMS, SUMSQ);
  k_ln_fin<<<36, 256, 0, stream>>>(SUMS, SUMSQ, MEAN, RSTD);
  k_ln1_win<<<dim3(144, 12), 256, 0, stream>>>(x, MEAN, RSTD, n1w, n1b, TOK);

  k_gemm8<<<9 * 36, 512, 0, stream>>>(TOK, WQ, qkv_b, BIG, 2304, 768, 9, 0);
  k_attn_mfma<<<864, 256, 0, stream>>>(BIG, BIASP, ATT);
  k_gemm_bt<<<6 * 72, 256, 0, stream>>>(ATT, WP, proj_b, PRJ, 768, 768, 6, 0);
  k_merge_win<<<dim3(144, 12), 256, 0, stream>>>(x, PRJ, X1);

  hipMemsetAsync(SUMS, 0, 2 * 9216 * 4, stream);
  k_ln_stats<<<dim3(36, 12), 256, 0, stream>>>(X1, SUMS, SUMSQ);
  k_ln_fin<<<36, 256, 0, stream>>>(SUMS, SUMSQ, MEAN, RSTD);
  k_ln2_raster<<<dim3(96, 12), 256, 0, stream>>>(X1, MEAN, RSTD, n2w, n2b, TOK);

  k_gemm8<<<12 * 36, 512, 0, stream>>>(TOK, W1, fc1_b, BIG, 3072, 768, 12, 1);
  k_gemm_bt<<<6 * 72, 256, 0, stream>>>(BIG, W2, fc2_b, ATT, 768, 3072, 6, 0);
  k_merge_raster<<<dim3(96, 12), 256, 0, stream>>>(X1, ATT, out);
}